// Round 1
// baseline (475.756 us; speedup 1.0000x reference)
//
#include <hip/hip_runtime.h>

// ---------------------------------------------------------------------------
// MultiChev: 3 ChebConv layers (K=1,2,3) shared graph, concat outputs.
// Round 5: XCD-private bucketed CSR build — workgroup-scope (L2-local)
//          atomics on per-XCD interleaved counters + 4-edge/thread ILP.
// ---------------------------------------------------------------------------

typedef __attribute__((ext_vector_type(8))) short short8;
typedef __attribute__((ext_vector_type(8))) unsigned short ushort8;
typedef __attribute__((ext_vector_type(4))) float f32x4;

__device__ inline float bf2f(unsigned short u) {
    return __uint_as_float(((unsigned int)u) << 16);
}
__device__ inline unsigned short f2bf(float f) {
    unsigned int u = __float_as_uint(f);
    u = (u + 0x7FFF + ((u >> 16) & 1)) >> 16;  // RNE
    return (unsigned short)u;
}

// Physical XCD id (0..7). HW-verified on MI355X (learn_hip m09). Wave-uniform.
__device__ inline unsigned xcc_id() {
    unsigned x;
    asm("s_getreg_b32 %0, hwreg(HW_REG_XCC_ID)" : "=s"(x));
    return x & 7u;
}

// Workgroup-scope atomics: lowered to global_atomic without L2 bypass ->
// executed in this XCD's L2. Correct here because each XCD only ever
// touches its own (addr%8==xcd) words / its own 128B bucket segments.
__device__ inline float atomAddL(float* p, float v) {
    return __hip_atomic_fetch_add(p, v, __ATOMIC_RELAXED, __HIP_MEMORY_SCOPE_WORKGROUP);
}
__device__ inline int atomAddL(int* p, int v) {
    return __hip_atomic_fetch_add(p, v, __ATOMIC_RELAXED, __HIP_MEMORY_SCOPE_WORKGROUP);
}

// ---- main path: per-XCD bucket build, 4 edges/thread (vector loads) ------
__global__ void scatter_xcd4_kernel(const int* __restrict__ row, const int* __restrict__ col,
                                    const float* __restrict__ ew, float* __restrict__ deg8,
                                    int* __restrict__ cnt8, uint2* __restrict__ erec,
                                    int E, int capx) {
    const unsigned xcd = xcc_id();
    int e0 = (blockIdx.x * 256 + threadIdx.x) * 4;
    if (e0 + 3 < E) {
        int4 r = *reinterpret_cast<const int4*>(row + e0);
        int4 c = *reinterpret_cast<const int4*>(col + e0);
        float4 w = *reinterpret_cast<const float4*>(ew + e0);
        atomAddL(&deg8[(size_t)r.x * 8 + xcd], w.x);
        atomAddL(&deg8[(size_t)r.y * 8 + xcd], w.y);
        atomAddL(&deg8[(size_t)r.z * 8 + xcd], w.z);
        atomAddL(&deg8[(size_t)r.w * 8 + xcd], w.w);
        int p0 = atomAddL(&cnt8[(size_t)c.x * 8 + xcd], 1);
        int p1 = atomAddL(&cnt8[(size_t)c.y * 8 + xcd], 1);
        int p2 = atomAddL(&cnt8[(size_t)c.z * 8 + xcd], 1);
        int p3 = atomAddL(&cnt8[(size_t)c.w * 8 + xcd], 1);
        if (p0 < capx) erec[((size_t)c.x * 8 + xcd) * capx + p0] = make_uint2((unsigned)r.x, __float_as_uint(w.x));
        if (p1 < capx) erec[((size_t)c.y * 8 + xcd) * capx + p1] = make_uint2((unsigned)r.y, __float_as_uint(w.y));
        if (p2 < capx) erec[((size_t)c.z * 8 + xcd) * capx + p2] = make_uint2((unsigned)r.z, __float_as_uint(w.z));
        if (p3 < capx) erec[((size_t)c.w * 8 + xcd) * capx + p3] = make_uint2((unsigned)r.w, __float_as_uint(w.w));
    } else if (e0 < E) {
        for (int e = e0; e < E; ++e) {
            int r = row[e], c = col[e];
            float w = ew[e];
            atomAddL(&deg8[(size_t)r * 8 + xcd], w);
            int p = atomAddL(&cnt8[(size_t)c * 8 + xcd], 1);
            if (p < capx) erec[((size_t)c * 8 + xcd) * capx + p] = make_uint2((unsigned)r, __float_as_uint(w));
        }
    }
}

// scalar variant (used when E % 4 != 0: col base not 16B-aligned)
__global__ void scatter_xcd1_kernel(const int* __restrict__ row, const int* __restrict__ col,
                                    const float* __restrict__ ew, float* __restrict__ deg8,
                                    int* __restrict__ cnt8, uint2* __restrict__ erec,
                                    int E, int capx) {
    const unsigned xcd = xcc_id();
    int e = blockIdx.x * 256 + threadIdx.x;
    if (e < E) {
        int r = row[e], c = col[e];
        float w = ew[e];
        atomAddL(&deg8[(size_t)r * 8 + xcd], w);
        int p = atomAddL(&cnt8[(size_t)c * 8 + xcd], 1);
        if (p < capx) erec[((size_t)c * 8 + xcd) * capx + p] = make_uint2((unsigned)r, __float_as_uint(w));
    }
}

// ---- fallback path (compact CSR, device-scope atomics) -------------------
__global__ void deg_count_kernel(const int* __restrict__ row, const int* __restrict__ col,
                                 const float* __restrict__ ew,
                                 float* __restrict__ deg, int* __restrict__ cnt, int E) {
    int e = blockIdx.x * 256 + threadIdx.x;
    if (e < E) {
        atomicAdd(&deg[row[e]], ew[e]);
        atomicAdd(&cnt[col[e]], 1);
    }
}

__global__ void scan1_kernel(const int* __restrict__ cnt, int* __restrict__ pre,
                             int* __restrict__ bsum, int N) {
    __shared__ int s[256];
    int t = threadIdx.x;
    int i = blockIdx.x * 256 + t;
    int v = (i < N) ? cnt[i] : 0;
    s[t] = v;
    __syncthreads();
    for (int o = 1; o < 256; o <<= 1) {
        int u = (t >= o) ? s[t - o] : 0;
        __syncthreads();
        s[t] += u;
        __syncthreads();
    }
    if (i < N) pre[i] = s[t] - v;
    if (t == 255) bsum[blockIdx.x] = s[255];
}

__global__ void scan2_kernel(const int* __restrict__ bsum, int* __restrict__ bpre, int nb) {
    __shared__ int s[512];
    int t = threadIdx.x;
    int v = (t < nb) ? bsum[t] : 0;
    s[t] = v;
    __syncthreads();
    for (int o = 1; o < 512; o <<= 1) {
        int u = (t >= o) ? s[t - o] : 0;
        __syncthreads();
        s[t] += u;
        __syncthreads();
    }
    if (t < nb) bpre[t] = s[t] - v;
}

__global__ void scan3_kernel(int* __restrict__ rowptr, int* __restrict__ cursor,
                             const int* __restrict__ bpre, int N, int E) {
    int i = blockIdx.x * 256 + threadIdx.x;
    if (i < N) {
        int v = rowptr[i] + bpre[i >> 8];
        rowptr[i] = v;
        cursor[i] = v;
    }
    if (i == 0) rowptr[N] = E;
}

__global__ void scatter_compact_kernel(const int* __restrict__ row, const int* __restrict__ col,
                                       const float* __restrict__ ew, int* __restrict__ cursor,
                                       uint2* __restrict__ erec, int E) {
    int e = blockIdx.x * 256 + threadIdx.x;
    if (e < E) {
        int p = atomicAdd(&cursor[col[e]], 1);
        erec[p] = make_uint2((unsigned)row[e], __float_as_uint(ew[e]));
    }
}

// ---- x -> bf16, and deg (possibly 8-way partial) -> dis ------------------
__global__ void cvt_dis_kernel(const float* __restrict__ x, unsigned short* __restrict__ xb,
                               const float* __restrict__ deg, float* __restrict__ dis,
                               int N, int total4, int dstride) {
    int i = blockIdx.x * 256 + threadIdx.x;
    if (i < total4) {
        float4 v = reinterpret_cast<const float4*>(x)[i];
        ushort4 o;
        o.x = f2bf(v.x); o.y = f2bf(v.y); o.z = f2bf(v.z); o.w = f2bf(v.w);
        reinterpret_cast<ushort4*>(xb)[i] = o;
    }
    if (i < N) {
        float d;
        if (dstride == 8) {
            float4 a = reinterpret_cast<const float4*>(deg)[i * 2];
            float4 b = reinterpret_cast<const float4*>(deg)[i * 2 + 1];
            d = ((a.x + a.y) + (a.z + a.w)) + ((b.x + b.y) + (b.z + b.w));
        } else {
            d = deg[i];
        }
        dis[i] = (d > 0.f) ? rsqrtf(d) : 0.f;
    }
}

// ---- gather prop: one wave per dst node, lane = channel ------------------
__device__ inline void chunk_fma(int ex, float w, int n, int lane,
                                 const unsigned short* __restrict__ src, float& acc) {
    int n4 = (n + 3) & ~3;
    for (int j = 0; j < n4; j += 4) {
        int r0 = __shfl(ex, j + 0, 64);
        int r1 = __shfl(ex, j + 1, 64);
        int r2 = __shfl(ex, j + 2, 64);
        int r3 = __shfl(ex, j + 3, 64);
        float w0 = __shfl(w, j + 0, 64);
        float w1 = __shfl(w, j + 1, 64);
        float w2 = __shfl(w, j + 2, 64);
        float w3 = __shfl(w, j + 3, 64);
        float v0 = bf2f(src[(size_t)r0 * 64 + lane]);
        float v1 = bf2f(src[(size_t)r1 * 64 + lane]);
        float v2 = bf2f(src[(size_t)r2 * 64 + lane]);
        float v3 = bf2f(src[(size_t)r3 * 64 + lane]);
        acc = fmaf(w0, v0, acc);
        acc = fmaf(w1, v1, acc);
        acc = fmaf(w2, v2, acc);
        acc = fmaf(w3, v3, acc);
    }
}

// xcdmode=1: 8 per-XCD segments of <=capx records, flattened via register
// prefix (all static indexing; runtime k only feeds address arithmetic).
// xcdmode=0: compact CSR (ptr[node]..ptr[node+1]).
__global__ void gather_kernel(const int* __restrict__ ptr, const int* __restrict__ cnt8,
                              const uint2* __restrict__ erec, const float* __restrict__ dis,
                              const unsigned short* __restrict__ src,
                              unsigned short* __restrict__ dst, int N, int xcdmode, int capx) {
    int node = blockIdx.x * 4 + (threadIdx.x >> 6);
    int lane = threadIdx.x & 63;
    if (node >= N) return;
    float acc = 0.f;
    if (xcdmode) {
        int4 ca = *reinterpret_cast<const int4*>(cnt8 + (size_t)node * 8);
        int4 cb = *reinterpret_cast<const int4*>(cnt8 + (size_t)node * 8 + 4);
        int p1 = min(ca.x, capx);
        int p2 = p1 + min(ca.y, capx);
        int p3 = p2 + min(ca.z, capx);
        int p4 = p3 + min(ca.w, capx);
        int p5 = p4 + min(cb.x, capx);
        int p6 = p5 + min(cb.y, capx);
        int p7 = p6 + min(cb.z, capx);
        int d  = p7 + min(cb.w, capx);
        const uint2* eb = erec + (size_t)node * 8 * capx;
        for (int base = 0; base < d; base += 64) {
            int n = min(64, d - base);
            int ex = 0;
            float w = 0.f;
            int flat = base + lane;
            if (flat < d) {
                int k = 0, pk = 0;
                if (flat >= p1) { k = 1; pk = p1; }
                if (flat >= p2) { k = 2; pk = p2; }
                if (flat >= p3) { k = 3; pk = p3; }
                if (flat >= p4) { k = 4; pk = p4; }
                if (flat >= p5) { k = 5; pk = p5; }
                if (flat >= p6) { k = 6; pk = p6; }
                if (flat >= p7) { k = 7; pk = p7; }
                uint2 e = eb[k * capx + (flat - pk)];
                ex = (int)e.x;
                w = __uint_as_float(e.y) * dis[ex];
            }
            chunk_fma(ex, w, n, lane, src, acc);
        }
    } else {
        int s = ptr[node];
        int d = ptr[node + 1] - s;
        for (int base = 0; base < d; base += 64) {
            int n = min(64, d - base);
            int ex = 0;
            float w = 0.f;
            if (lane < n) {
                uint2 e = erec[s + base + lane];
                ex = (int)e.x;
                w = __uint_as_float(e.y) * dis[ex];
            }
            chunk_fma(ex, w, n, lane, src, acc);
        }
    }
    dst[(size_t)node * 64 + lane] = f2bf(-dis[node] * acc);
}

// ---- W pre-pack into swizzled bf16 LDS images ----------------------------
__global__ void prep_w_kernel(const float* __restrict__ W10, const float* __restrict__ W20,
                              const float* __restrict__ W21, const float* __restrict__ W30,
                              const float* __restrict__ W31, const float* __restrict__ W32,
                              unsigned short* __restrict__ imgW) {
    int i = blockIdx.x * 256 + threadIdx.x;
    if (i >= 6 * 7168) return;
    int img = i / 7168;
    int rem = i - img * 7168;
    int colc = rem >> 6;
    int k = rem & 63;
    const float* W;
    switch (img) {
        case 0: W = W10; break;
        case 1: W = W20; break;
        case 2: W = W21; break;
        case 3: W = W30; break;
        case 4: W = W31; break;
        default: W = W32; break;
    }
    float v = (colc < 100) ? W[k * 100 + colc] : 0.f;
    int g = k >> 3, j = k & 7;
    imgW[img * 7168 + colc * 64 + ((g ^ (colc & 7)) << 3) + j] = f2bf(v);
}

// ---- MFMA gemm: block = 64 rows x one segment (100 cols, padded 112) -----
__global__ __launch_bounds__(256) void gemm_mfma_kernel(
        const unsigned short* __restrict__ xb, const unsigned short* __restrict__ tx1b,
        const unsigned short* __restrict__ p2b, const unsigned short* __restrict__ imgW,
        const float* __restrict__ b1, const float* __restrict__ b2,
        const float* __restrict__ b3, float* __restrict__ out, int N) {
    __shared__ unsigned short Ft[64 * 64];
    __shared__ unsigned short Ws[112 * 64];
    const int bid = blockIdx.x;
    const int seg = bid % 3;
    const int tile = bid / 3;
    const int row0 = tile * 64;
    const int tid = threadIdx.x;
    const int wv = tid >> 6;
    const int l = tid & 63;
    const int m = l & 15;
    const int q = l >> 4;

    f32x4 acc[7];
#pragma unroll
    for (int t = 0; t < 7; ++t) acc[t] = (f32x4){0.f, 0.f, 0.f, 0.f};

    const int imgBase = (seg * (seg + 1) / 2) * 7168;

    for (int c = 0; c <= seg; ++c) {
        const unsigned short* __restrict__ src = (c == 0) ? xb : (c == 1) ? tx1b : p2b;
#pragma unroll
        for (int it = 0; it < 2; ++it) {
            int i = tid + it * 256;
            int r = i >> 3, g = i & 7;
            int grow = row0 + r;
            ushort8 v = {0, 0, 0, 0, 0, 0, 0, 0};
            if (grow < N) {
                v = *reinterpret_cast<const ushort8*>(src + (size_t)grow * 64 + g * 8);
                if (c == 2) {  // tx2 = 2*p2 - x on the fly
                    ushort8 xv = *reinterpret_cast<const ushort8*>(xb + (size_t)grow * 64 + g * 8);
#pragma unroll
                    for (int jj = 0; jj < 8; ++jj)
                        v[jj] = f2bf(2.f * bf2f(v[jj]) - bf2f(xv[jj]));
                }
            }
            *reinterpret_cast<ushort8*>(&Ft[r * 64 + ((g ^ (r & 7)) << 3)]) = v;
        }
        const uint4* wsrc = reinterpret_cast<const uint4*>(imgW + imgBase + c * 7168);
        uint4* wdst = reinterpret_cast<uint4*>(Ws);
#pragma unroll
        for (int it = 0; it < 4; ++it) {
            int i = tid + it * 256;
            if (i < 896) wdst[i] = wsrc[i];
        }
        __syncthreads();

        const int arow = wv * 16 + m;
#pragma unroll
        for (int ks = 0; ks < 2; ++ks) {
            short8 a = *reinterpret_cast<const short8*>(
                &Ft[arow * 64 + (((ks * 4 + q) ^ (arow & 7)) << 3)]);
#pragma unroll
            for (int t = 0; t < 7; ++t) {
                int n = t * 16 + m;
                short8 b = *reinterpret_cast<const short8*>(
                    &Ws[n * 64 + (((ks * 4 + q) ^ (n & 7)) << 3)]);
                acc[t] = __builtin_amdgcn_mfma_f32_16x16x32_bf16(a, b, acc[t], 0, 0, 0);
            }
        }
        __syncthreads();
    }

    const float* bsel = (seg == 0) ? b1 : (seg == 1) ? b2 : b3;
#pragma unroll
    for (int t = 0; t < 7; ++t) {
        int colseg = t * 16 + m;
        if (colseg >= 100) continue;
        float bv = bsel[colseg];
#pragma unroll
        for (int i = 0; i < 4; ++i) {
            int grow = row0 + wv * 16 + q * 4 + i;
            if (grow < N) out[(size_t)grow * 300 + seg * 100 + colseg] = acc[t][i] + bv;
        }
    }
}

extern "C" void kernel_launch(void* const* d_in, const int* in_sizes, int n_in,
                              void* d_out, int out_size, void* d_ws, size_t ws_size,
                              hipStream_t stream) {
    const float* x   = (const float*)d_in[0];
    const int*   ei  = (const int*)d_in[1];
    const float* ew  = (const float*)d_in[2];
    const float* W10 = (const float*)d_in[3];
    const float* b1  = (const float*)d_in[4];
    const float* W20 = (const float*)d_in[5];
    const float* W21 = (const float*)d_in[6];
    const float* b2  = (const float*)d_in[7];
    const float* W30 = (const float*)d_in[8];
    const float* W31 = (const float*)d_in[9];
    const float* W32 = (const float*)d_in[10];
    const float* b3  = (const float*)d_in[11];
    float* out = (float*)d_out;

    const int N = in_sizes[0] / 64;
    const int E = in_sizes[2];
    const int* row = ei;
    const int* col = ei + E;
    const int nb = (N + 255) / 256;
    const int eb = (E + 255) / 256;

    char* base = (char*)d_ws;
    size_t off = 0;
    auto alloc = [&](size_t bytes) { size_t o = off; off = (off + bytes + 15) & ~(size_t)15; return o; };

    // common allocations
    float* dis           = (float*)(base + alloc((size_t)4 * N));
    float* deg8          = (float*)(base + alloc((size_t)32 * N));   // 8 partials/node
    int*   cnt8          = (int*)(base + alloc((size_t)32 * N));     // adjacent to deg8
    unsigned short* xb   = (unsigned short*)(base + alloc((size_t)128 * N));
    unsigned short* tx1b = (unsigned short*)(base + alloc((size_t)128 * N));
    unsigned short* p2b  = (unsigned short*)(base + alloc((size_t)128 * N));
    unsigned short* imgW = (unsigned short*)(base + alloc((size_t)2 * 6 * 7168));
    size_t common = off;

    int total4 = N * 16;
    int pg = (N + 3) / 4;
    int ntile = (N + 63) / 64;

    // pick largest per-XCD capacity that fits the workspace
    int capx = 0;
    if (common + (size_t)8 * N * 8 * 16 + 64 <= ws_size) capx = 16;
    else if (common + (size_t)8 * N * 8 * 12 + 64 <= ws_size) capx = 12;

    if (capx > 0) {
        uint2* erec = (uint2*)(base + alloc((size_t)8 * N * 8 * capx));

        hipMemsetAsync(deg8, 0, (size_t)64 * N, stream);  // deg8 + cnt8 (adjacent)
        if ((E & 3) == 0) {
            int ebv = (E / 4 + 255) / 256;
            scatter_xcd4_kernel<<<ebv, 256, 0, stream>>>(row, col, ew, deg8, cnt8, erec, E, capx);
        } else {
            scatter_xcd1_kernel<<<eb, 256, 0, stream>>>(row, col, ew, deg8, cnt8, erec, E, capx);
        }
        cvt_dis_kernel<<<(total4 + 255) / 256, 256, 0, stream>>>(x, xb, deg8, dis, N, total4, 8);
        prep_w_kernel<<<(6 * 7168 + 255) / 256, 256, 0, stream>>>(W10, W20, W21, W30, W31, W32, imgW);

        gather_kernel<<<pg, 256, 0, stream>>>(nullptr, cnt8, erec, dis, xb, tx1b, N, 1, capx);
        gather_kernel<<<pg, 256, 0, stream>>>(nullptr, cnt8, erec, dis, tx1b, p2b, N, 1, capx);
        gemm_mfma_kernel<<<ntile * 3, 256, 0, stream>>>(xb, tx1b, p2b, imgW, b1, b2, b3, out, N);
    } else {
        // compact-CSR fallback (device-scope atomics); reuses deg8[0..N), cnt8[0..N)
        float* deg    = deg8;
        int*   cursor = cnt8;
        int*   rowptr = (int*)(base + alloc((size_t)4 * (N + 1)));
        int*   bsum   = (int*)(base + alloc((size_t)4 * nb));
        int*   bpre   = (int*)(base + alloc((size_t)4 * nb));
        uint2* erec   = (uint2*)(base + alloc((size_t)8 * E));

        hipMemsetAsync(deg, 0, (size_t)4 * N, stream);
        hipMemsetAsync(cursor, 0, (size_t)4 * N, stream);
        deg_count_kernel<<<eb, 256, 0, stream>>>(row, col, ew, deg, cursor, E);
        scan1_kernel<<<nb, 256, 0, stream>>>(cursor, rowptr, bsum, N);
        scan2_kernel<<<1, 512, 0, stream>>>(bsum, bpre, nb);
        scan3_kernel<<<nb, 256, 0, stream>>>(rowptr, cursor, bpre, N, E);
        scatter_compact_kernel<<<eb, 256, 0, stream>>>(row, col, ew, cursor, erec, E);
        cvt_dis_kernel<<<(total4 + 255) / 256, 256, 0, stream>>>(x, xb, deg, dis, N, total4, 1);
        prep_w_kernel<<<(6 * 7168 + 255) / 256, 256, 0, stream>>>(W10, W20, W21, W30, W31, W32, imgW);

        gather_kernel<<<pg, 256, 0, stream>>>(rowptr, nullptr, erec, dis, xb, tx1b, N, 0, 0);
        gather_kernel<<<pg, 256, 0, stream>>>(rowptr, nullptr, erec, dis, tx1b, p2b, N, 0, 0);
        gemm_mfma_kernel<<<ntile * 3, 256, 0, stream>>>(xb, tx1b, p2b, imgW, b1, b2, b3, out, N);
    }
}

// Round 2
// 414.065 us; speedup vs baseline: 1.1490x; 1.1490x over previous
//
#include <hip/hip_runtime.h>

// ---------------------------------------------------------------------------
// MultiChev: 3 ChebConv layers (K=1,2,3) shared graph, concat outputs.
// Round 6: atomic-free CSR build via two-level LDS-histogram partition.
//   Diagnosis r0/r1: per-edge atomics ceiling ~36 G/s (5M atomics = 135 us,
//   invariant to scope/layout) + 64B-line thrash on random 8B stores.
//   Fix: block-level bulk reservation (~400K atomics total) + bucket-local
//   writes that stay L2-resident. deg computed per-bucket in LDS (no global
//   atomics); dis[row] folded into edge records (saves a random load in
//   both gather passes).
// ---------------------------------------------------------------------------

typedef __attribute__((ext_vector_type(8))) short short8;
typedef __attribute__((ext_vector_type(8))) unsigned short ushort8;
typedef __attribute__((ext_vector_type(4))) float f32x4;

#define CAPB 8192           // records per 256-col/row bucket (mean 6400, +22 sigma)
#define MAXBUCK 512         // max buckets supported by part_kernel LDS

__device__ inline float bf2f(unsigned short u) {
    return __uint_as_float(((unsigned int)u) << 16);
}
__device__ inline unsigned short f2bf(float f) {
    unsigned int u = __float_as_uint(f);
    u = (u + 0x7FFF + ((u >> 16) & 1)) >> 16;  // RNE
    return (unsigned short)u;
}

// ---- pass 1: partition edges into 256-wide col buckets AND row buckets ---
// One contiguous chunk per block. LDS histograms -> one bulk-reserve atomic
// per (block, nonempty bin) -> per-edge LDS-rank placement. colpart record:
// x = (col&255)<<24 | row, y = w. rowpart record: x = row, y = w.
__global__ __launch_bounds__(256) void part_kernel(
        const int* __restrict__ row, const int* __restrict__ col,
        const float* __restrict__ ew, int* __restrict__ colcur,
        int* __restrict__ rowcur, uint2* __restrict__ colpart,
        uint2* __restrict__ rowpart, int E, int nbuck, int chunk) {
    __shared__ int hc[MAXBUCK];
    __shared__ int hr[MAXBUCK];
    const int t = threadIdx.x;
    const int s = blockIdx.x * chunk;
    const int e = min(E, s + chunk);
    if (s >= E) return;
    for (int i = t; i < nbuck; i += 256) { hc[i] = 0; hr[i] = 0; }
    __syncthreads();
    for (int i = s + t; i < e; i += 256) {
        atomicAdd(&hc[col[i] >> 8], 1);
        atomicAdd(&hr[row[i] >> 8], 1);
    }
    __syncthreads();
    // bulk reservation: hc/hr become within-bucket base cursors
    for (int i = t; i < nbuck; i += 256) {
        int n = hc[i];
        hc[i] = n ? atomicAdd(&colcur[i], n) : 0;
        n = hr[i];
        hr[i] = n ? atomicAdd(&rowcur[i], n) : 0;
    }
    __syncthreads();
    for (int i = s + t; i < e; i += 256) {
        int r = row[i], c = col[i];
        float w = ew[i];
        int cb = c >> 8, rb = r >> 8;
        int pc = atomicAdd(&hc[cb], 1);   // within-bucket slot
        if (pc < CAPB)
            colpart[(size_t)cb * CAPB + pc] =
                make_uint2(((unsigned)(c & 255) << 24) | (unsigned)r, __float_as_uint(w));
        int pr = atomicAdd(&hr[rb], 1);
        if (pr < CAPB)
            rowpart[(size_t)rb * CAPB + pr] = make_uint2((unsigned)r, __float_as_uint(w));
    }
}

// ---- pass 2a: per row-bucket deg sums in LDS -> dis ----------------------
__global__ __launch_bounds__(256) void fine_row_kernel(
        const int* __restrict__ rowcur, const uint2* __restrict__ rowpart,
        float* __restrict__ dis, int N) {
    __shared__ float s[256];
    const int b = blockIdx.x, t = threadIdx.x;
    const int sz = min(rowcur[b], CAPB);
    const uint2* part = rowpart + (size_t)b * CAPB;
    s[t] = 0.f;
    __syncthreads();
    for (int i = t; i < sz; i += 256) {
        uint2 rec = part[i];
        atomicAdd(&s[rec.x & 255u], __uint_as_float(rec.y));
    }
    __syncthreads();
    int r = (b << 8) + t;
    if (r < N) {
        float d = s[t];
        dis[r] = (d > 0.f) ? rsqrtf(d) : 0.f;
    }
}

// ---- pass 2b: exclusive prefix over col-bucket sizes ---------------------
__global__ void colbase_scan_kernel(const int* __restrict__ colcur,
                                    int* __restrict__ colbase,
                                    int* __restrict__ rowptr, int N, int nbuck) {
    __shared__ int s[MAXBUCK];
    int t = threadIdx.x;
    int v = (t < nbuck) ? min(colcur[t], CAPB) : 0;
    s[t] = v;
    __syncthreads();
    for (int o = 1; o < MAXBUCK; o <<= 1) {
        int u = (t >= o) ? s[t - o] : 0;
        __syncthreads();
        s[t] += u;
        __syncthreads();
    }
    if (t < nbuck) colbase[t] = s[t] - v;
    if (t == MAXBUCK - 1) rowptr[N] = s[MAXBUCK - 1];
}

// ---- pass 2c: per col-bucket fine CSR build ------------------------------
// Writes rowptr slice + erec records (r, w*dis[r]) grouped by col. All
// record writes land in this block's ~51KB bucket region (L2-resident).
__global__ __launch_bounds__(256) void fine_col_kernel(
        const int* __restrict__ colcur, const int* __restrict__ colbase,
        const uint2* __restrict__ colpart, const float* __restrict__ dis,
        uint2* __restrict__ erec, int* __restrict__ rowptr, int N) {
    __shared__ int h[256];
    __shared__ int sc[256];
    __shared__ int cur[256];
    const int b = blockIdx.x, t = threadIdx.x;
    const int sz = min(colcur[b], CAPB);
    const uint2* part = colpart + (size_t)b * CAPB;
    h[t] = 0;
    __syncthreads();
    for (int i = t; i < sz; i += 256) atomicAdd(&h[part[i].x >> 24], 1);
    __syncthreads();
    int v = h[t];
    sc[t] = v;
    __syncthreads();
    for (int o = 1; o < 256; o <<= 1) {
        int u = (t >= o) ? sc[t - o] : 0;
        __syncthreads();
        sc[t] += u;
        __syncthreads();
    }
    int excl = sc[t] - v;
    const int base = colbase[b];
    int c = (b << 8) + t;
    if (c < N) rowptr[c] = base + excl;
    cur[t] = excl;
    __syncthreads();
    for (int i = t; i < sz; i += 256) {
        uint2 rec = part[i];
        int coff = rec.x >> 24;
        int r = rec.x & 0xFFFFFFu;
        int pos = atomicAdd(&cur[coff], 1);
        float wd = __uint_as_float(rec.y) * dis[r];  // fold dis[row] into record
        erec[(size_t)base + pos] = make_uint2((unsigned)r, __float_as_uint(wd));
    }
}

// ---- fallback path (compact CSR, device-scope atomics) -------------------
__global__ void deg_count_kernel(const int* __restrict__ row, const int* __restrict__ col,
                                 const float* __restrict__ ew,
                                 float* __restrict__ deg, int* __restrict__ cnt, int E) {
    int e = blockIdx.x * 256 + threadIdx.x;
    if (e < E) {
        atomicAdd(&deg[row[e]], ew[e]);
        atomicAdd(&cnt[col[e]], 1);
    }
}

__global__ void scan1_kernel(const int* __restrict__ cnt, int* __restrict__ pre,
                             int* __restrict__ bsum, int N) {
    __shared__ int s[256];
    int t = threadIdx.x;
    int i = blockIdx.x * 256 + t;
    int v = (i < N) ? cnt[i] : 0;
    s[t] = v;
    __syncthreads();
    for (int o = 1; o < 256; o <<= 1) {
        int u = (t >= o) ? s[t - o] : 0;
        __syncthreads();
        s[t] += u;
        __syncthreads();
    }
    if (i < N) pre[i] = s[t] - v;
    if (t == 255) bsum[blockIdx.x] = s[255];
}

__global__ void scan2_kernel(const int* __restrict__ bsum, int* __restrict__ bpre, int nb) {
    __shared__ int s[512];
    int t = threadIdx.x;
    int v = (t < nb) ? bsum[t] : 0;
    s[t] = v;
    __syncthreads();
    for (int o = 1; o < 512; o <<= 1) {
        int u = (t >= o) ? s[t - o] : 0;
        __syncthreads();
        s[t] += u;
        __syncthreads();
    }
    if (t < nb) bpre[t] = s[t] - v;
}

__global__ void scan3_kernel(int* __restrict__ rowptr, int* __restrict__ cursor,
                             const int* __restrict__ bpre, int N, int E) {
    int i = blockIdx.x * 256 + threadIdx.x;
    if (i < N) {
        int v = rowptr[i] + bpre[i >> 8];
        rowptr[i] = v;
        cursor[i] = v;
    }
    if (i == 0) rowptr[N] = E;
}

__global__ void scatter_compact_kernel(const int* __restrict__ row, const int* __restrict__ col,
                                       const float* __restrict__ ew, int* __restrict__ cursor,
                                       uint2* __restrict__ erec, int E) {
    int e = blockIdx.x * 256 + threadIdx.x;
    if (e < E) {
        int p = atomicAdd(&cursor[col[e]], 1);
        erec[p] = make_uint2((unsigned)row[e], __float_as_uint(ew[e]));
    }
}

// ---- x -> bf16 (and optionally deg -> dis for fallback) ------------------
__global__ void cvt_dis_kernel(const float* __restrict__ x, unsigned short* __restrict__ xb,
                               const float* __restrict__ deg, float* __restrict__ dis,
                               int N, int total4, int dodis) {
    int i = blockIdx.x * 256 + threadIdx.x;
    if (i < total4) {
        float4 v = reinterpret_cast<const float4*>(x)[i];
        ushort4 o;
        o.x = f2bf(v.x); o.y = f2bf(v.y); o.z = f2bf(v.z); o.w = f2bf(v.w);
        reinterpret_cast<ushort4*>(xb)[i] = o;
    }
    if (dodis && i < N) {
        float d = deg[i];
        dis[i] = (d > 0.f) ? rsqrtf(d) : 0.f;
    }
}

// ---- gather prop: one wave per dst node, lane = channel ------------------
// premul=1: record.y already holds w*dis[row]; premul=0: multiply dis[row].
__global__ void gather_kernel(const int* __restrict__ ptr, const uint2* __restrict__ erec,
                              const float* __restrict__ dis,
                              const unsigned short* __restrict__ src,
                              unsigned short* __restrict__ dst, int N, int premul) {
    int node = blockIdx.x * 4 + (threadIdx.x >> 6);
    int lane = threadIdx.x & 63;
    if (node >= N) return;
    int s = ptr[node];
    int d = ptr[node + 1] - s;
    float acc = 0.f;
    for (int base = 0; base < d; base += 64) {
        int n = min(64, d - base);
        int ex = 0;
        float w = 0.f;
        if (lane < n) {
            uint2 e = erec[s + base + lane];
            ex = (int)e.x;
            w = __uint_as_float(e.y);
            if (!premul) w *= dis[ex];
        }
        int n4 = (n + 3) & ~3;
        for (int j = 0; j < n4; j += 4) {
            int r0 = __shfl(ex, j + 0, 64);
            int r1 = __shfl(ex, j + 1, 64);
            int r2 = __shfl(ex, j + 2, 64);
            int r3 = __shfl(ex, j + 3, 64);
            float w0 = __shfl(w, j + 0, 64);
            float w1 = __shfl(w, j + 1, 64);
            float w2 = __shfl(w, j + 2, 64);
            float w3 = __shfl(w, j + 3, 64);
            float v0 = bf2f(src[(size_t)r0 * 64 + lane]);
            float v1 = bf2f(src[(size_t)r1 * 64 + lane]);
            float v2 = bf2f(src[(size_t)r2 * 64 + lane]);
            float v3 = bf2f(src[(size_t)r3 * 64 + lane]);
            acc = fmaf(w0, v0, acc);
            acc = fmaf(w1, v1, acc);
            acc = fmaf(w2, v2, acc);
            acc = fmaf(w3, v3, acc);
        }
    }
    dst[(size_t)node * 64 + lane] = f2bf(-dis[node] * acc);
}

// ---- W pre-pack into swizzled bf16 LDS images ----------------------------
__global__ void prep_w_kernel(const float* __restrict__ W10, const float* __restrict__ W20,
                              const float* __restrict__ W21, const float* __restrict__ W30,
                              const float* __restrict__ W31, const float* __restrict__ W32,
                              unsigned short* __restrict__ imgW) {
    int i = blockIdx.x * 256 + threadIdx.x;
    if (i >= 6 * 7168) return;
    int img = i / 7168;
    int rem = i - img * 7168;
    int colc = rem >> 6;
    int k = rem & 63;
    const float* W;
    switch (img) {
        case 0: W = W10; break;
        case 1: W = W20; break;
        case 2: W = W21; break;
        case 3: W = W30; break;
        case 4: W = W31; break;
        default: W = W32; break;
    }
    float v = (colc < 100) ? W[k * 100 + colc] : 0.f;
    int g = k >> 3, j = k & 7;
    imgW[img * 7168 + colc * 64 + ((g ^ (colc & 7)) << 3) + j] = f2bf(v);
}

// ---- MFMA gemm: block = 64 rows x one segment (100 cols, padded 112) -----
__global__ __launch_bounds__(256) void gemm_mfma_kernel(
        const unsigned short* __restrict__ xb, const unsigned short* __restrict__ tx1b,
        const unsigned short* __restrict__ p2b, const unsigned short* __restrict__ imgW,
        const float* __restrict__ b1, const float* __restrict__ b2,
        const float* __restrict__ b3, float* __restrict__ out, int N) {
    __shared__ unsigned short Ft[64 * 64];
    __shared__ unsigned short Ws[112 * 64];
    const int bid = blockIdx.x;
    const int seg = bid % 3;
    const int tile = bid / 3;
    const int row0 = tile * 64;
    const int tid = threadIdx.x;
    const int wv = tid >> 6;
    const int l = tid & 63;
    const int m = l & 15;
    const int q = l >> 4;

    f32x4 acc[7];
#pragma unroll
    for (int t = 0; t < 7; ++t) acc[t] = (f32x4){0.f, 0.f, 0.f, 0.f};

    const int imgBase = (seg * (seg + 1) / 2) * 7168;

    for (int c = 0; c <= seg; ++c) {
        const unsigned short* __restrict__ src = (c == 0) ? xb : (c == 1) ? tx1b : p2b;
#pragma unroll
        for (int it = 0; it < 2; ++it) {
            int i = tid + it * 256;
            int r = i >> 3, g = i & 7;
            int grow = row0 + r;
            ushort8 v = {0, 0, 0, 0, 0, 0, 0, 0};
            if (grow < N) {
                v = *reinterpret_cast<const ushort8*>(src + (size_t)grow * 64 + g * 8);
                if (c == 2) {  // tx2 = 2*p2 - x on the fly
                    ushort8 xv = *reinterpret_cast<const ushort8*>(xb + (size_t)grow * 64 + g * 8);
#pragma unroll
                    for (int jj = 0; jj < 8; ++jj)
                        v[jj] = f2bf(2.f * bf2f(v[jj]) - bf2f(xv[jj]));
                }
            }
            *reinterpret_cast<ushort8*>(&Ft[r * 64 + ((g ^ (r & 7)) << 3)]) = v;
        }
        const uint4* wsrc = reinterpret_cast<const uint4*>(imgW + imgBase + c * 7168);
        uint4* wdst = reinterpret_cast<uint4*>(Ws);
#pragma unroll
        for (int it = 0; it < 4; ++it) {
            int i = tid + it * 256;
            if (i < 896) wdst[i] = wsrc[i];
        }
        __syncthreads();

        const int arow = wv * 16 + m;
#pragma unroll
        for (int ks = 0; ks < 2; ++ks) {
            short8 a = *reinterpret_cast<const short8*>(
                &Ft[arow * 64 + (((ks * 4 + q) ^ (arow & 7)) << 3)]);
#pragma unroll
            for (int t = 0; t < 7; ++t) {
                int n = t * 16 + m;
                short8 b = *reinterpret_cast<const short8*>(
                    &Ws[n * 64 + (((ks * 4 + q) ^ (n & 7)) << 3)]);
                acc[t] = __builtin_amdgcn_mfma_f32_16x16x32_bf16(a, b, acc[t], 0, 0, 0);
            }
        }
        __syncthreads();
    }

    const float* bsel = (seg == 0) ? b1 : (seg == 1) ? b2 : b3;
#pragma unroll
    for (int t = 0; t < 7; ++t) {
        int colseg = t * 16 + m;
        if (colseg >= 100) continue;
        float bv = bsel[colseg];
#pragma unroll
        for (int i = 0; i < 4; ++i) {
            int grow = row0 + wv * 16 + q * 4 + i;
            if (grow < N) out[(size_t)grow * 300 + seg * 100 + colseg] = acc[t][i] + bv;
        }
    }
}

extern "C" void kernel_launch(void* const* d_in, const int* in_sizes, int n_in,
                              void* d_out, int out_size, void* d_ws, size_t ws_size,
                              hipStream_t stream) {
    const float* x   = (const float*)d_in[0];
    const int*   ei  = (const int*)d_in[1];
    const float* ew  = (const float*)d_in[2];
    const float* W10 = (const float*)d_in[3];
    const float* b1  = (const float*)d_in[4];
    const float* W20 = (const float*)d_in[5];
    const float* W21 = (const float*)d_in[6];
    const float* b2  = (const float*)d_in[7];
    const float* W30 = (const float*)d_in[8];
    const float* W31 = (const float*)d_in[9];
    const float* W32 = (const float*)d_in[10];
    const float* b3  = (const float*)d_in[11];
    float* out = (float*)d_out;

    const int N = in_sizes[0] / 64;
    const int E = in_sizes[2];
    const int* row = ei;
    const int* col = ei + E;
    const int nb = (N + 255) / 256;
    const int eb = (E + 255) / 256;
    const int nbuck = (N + 255) >> 8;

    int total4 = N * 16;
    int pg = (N + 3) / 4;
    int ntile = (N + 63) / 64;

    char* base = (char*)d_ws;
    size_t off = 0;
    auto alloc = [&](size_t bytes) { size_t o = off; off = (off + bytes + 15) & ~(size_t)15; return o; };

    // ---- main-path layout ----
    float* dis           = (float*)(base + alloc((size_t)4 * N));
    int*   rowptr        = (int*)(base + alloc((size_t)4 * (N + 1)));
    int*   colcur        = (int*)(base + alloc((size_t)4 * MAXBUCK * 2));  // colcur + rowcur
    int*   rowcur        = colcur + MAXBUCK;
    int*   colbase       = (int*)(base + alloc((size_t)4 * MAXBUCK));
    unsigned short* xb   = (unsigned short*)(base + alloc((size_t)128 * N));
    unsigned short* tx1b = (unsigned short*)(base + alloc((size_t)128 * N));
    unsigned short* p2b  = (unsigned short*)(base + alloc((size_t)128 * N));
    unsigned short* imgW = (unsigned short*)(base + alloc((size_t)2 * 6 * 7168));
    uint2* erec          = (uint2*)(base + alloc((size_t)8 * E));
    size_t mainfix = off;
    uint2* colpart       = (uint2*)(base + alloc((size_t)8 * nbuck * CAPB));
    uint2* rowpart       = (uint2*)(base + alloc((size_t)8 * nbuck * CAPB));
    size_t mainneed = off;

    bool mainok = (N < (1 << 24)) && (nbuck <= MAXBUCK) && (mainneed <= ws_size);

    if (mainok) {
        const int PBLK = 512;
        int chunk = (E + PBLK - 1) / PBLK;

        hipMemsetAsync(colcur, 0, (size_t)4 * MAXBUCK * 2, stream);
        part_kernel<<<PBLK, 256, 0, stream>>>(row, col, ew, colcur, rowcur,
                                              colpart, rowpart, E, nbuck, chunk);
        fine_row_kernel<<<nbuck, 256, 0, stream>>>(rowcur, rowpart, dis, N);
        colbase_scan_kernel<<<1, MAXBUCK, 0, stream>>>(colcur, colbase, rowptr, N, nbuck);
        fine_col_kernel<<<nbuck, 256, 0, stream>>>(colcur, colbase, colpart, dis,
                                                   erec, rowptr, N);
        cvt_dis_kernel<<<(total4 + 255) / 256, 256, 0, stream>>>(x, xb, nullptr, nullptr,
                                                                 N, total4, 0);
        prep_w_kernel<<<(6 * 7168 + 255) / 256, 256, 0, stream>>>(W10, W20, W21, W30, W31, W32, imgW);

        gather_kernel<<<pg, 256, 0, stream>>>(rowptr, erec, dis, xb, tx1b, N, 1);
        gather_kernel<<<pg, 256, 0, stream>>>(rowptr, erec, dis, tx1b, p2b, N, 1);
        gemm_mfma_kernel<<<ntile * 3, 256, 0, stream>>>(xb, tx1b, p2b, imgW, b1, b2, b3, out, N);
    } else {
        // ---- compact-CSR fallback (device-scope atomics) ----
        off = mainfix;  // reuse fixed allocations; add fallback scratch after erec
        float* deg    = (float*)(base + alloc((size_t)4 * N));
        int*   cursor = (int*)(base + alloc((size_t)4 * N));
        int*   bsum   = (int*)(base + alloc((size_t)4 * nb));
        int*   bpre   = (int*)(base + alloc((size_t)4 * nb));

        hipMemsetAsync(deg, 0, (size_t)4 * N, stream);
        hipMemsetAsync(cursor, 0, (size_t)4 * N, stream);
        deg_count_kernel<<<eb, 256, 0, stream>>>(row, col, ew, deg, cursor, E);
        scan1_kernel<<<nb, 256, 0, stream>>>(cursor, rowptr, bsum, N);
        scan2_kernel<<<1, 512, 0, stream>>>(bsum, bpre, nb);
        scan3_kernel<<<nb, 256, 0, stream>>>(rowptr, cursor, bpre, N, E);
        scatter_compact_kernel<<<eb, 256, 0, stream>>>(row, col, ew, cursor, erec, E);
        cvt_dis_kernel<<<(total4 + 255) / 256, 256, 0, stream>>>(x, xb, deg, dis, N, total4, 1);
        prep_w_kernel<<<(6 * 7168 + 255) / 256, 256, 0, stream>>>(W10, W20, W21, W30, W31, W32, imgW);

        gather_kernel<<<pg, 256, 0, stream>>>(rowptr, erec, dis, xb, tx1b, N, 0);
        gather_kernel<<<pg, 256, 0, stream>>>(rowptr, erec, dis, tx1b, p2b, N, 0);
        gemm_mfma_kernel<<<ntile * 3, 256, 0, stream>>>(xb, tx1b, p2b, imgW, b1, b2, b3, out, N);
    }
}

// Round 4
// 386.549 us; speedup vs baseline: 1.2308x; 1.0712x over previous
//
#include <hip/hip_runtime.h>

// ---------------------------------------------------------------------------
// MultiChev: 3 ChebConv layers (K=1,2,3) shared graph, concat outputs.
// Round 8 (= R7 resubmit; container infra failure last round, code audited
// clean): two-level hierarchical partition for the CSR build.
//   r2 diagnosis: part_kernel wrote 75MB for 20MB of records (runs of 12.5
//   recs = 100B per (block,bucket) -> partial-line thrash) at 19% occupancy.
//   Fix: level A bins into 49 super-buckets (runs ~400B, amp ~1.1x) at 16
//   waves/CU; level B splits each super into 8 fine buckets (runs ~1.2KB).
//   deg via per-super LDS partial sums (no global atomics), reduced in cvt.
// ---------------------------------------------------------------------------

typedef __attribute__((ext_vector_type(8))) short short8;
typedef __attribute__((ext_vector_type(8))) unsigned short ushort8;
typedef __attribute__((ext_vector_type(4))) float f32x4;

#define NSBMAX 64       // max super-buckets (2048 nodes each) -> N <= 131072
#define NSPLIT 16       // blocks per super-bucket in level-B kernels

__device__ inline float bf2f(unsigned short u) {
    return __uint_as_float(((unsigned int)u) << 16);
}
__device__ inline unsigned short f2bf(float f) {
    unsigned int u = __float_as_uint(f);
    u = (u + 0x7FFF + ((u >> 16) & 1)) >> 16;  // RNE
    return (unsigned short)u;
}

// ---- level A: bin edges into 2048-node super-buckets (col AND row) -------
// colA record: meta = (c&2047)<<17 | r  (r<2^17), w.  rowA record: (r, w).
__global__ __launch_bounds__(512) void partA_kernel(
        const int* __restrict__ row, const int* __restrict__ col,
        const float* __restrict__ ew, int* __restrict__ colAcur,
        int* __restrict__ rowAcur, uint2* __restrict__ colA,
        uint2* __restrict__ rowA, int E, int nsb, int chunk, int capA) {
    __shared__ int hc[NSBMAX];
    __shared__ int hr[NSBMAX];
    const int t = threadIdx.x;
    const int s = blockIdx.x * chunk;
    const int e = min(E, s + chunk);
    if (s >= E) return;
    if (t < NSBMAX) { hc[t] = 0; hr[t] = 0; }
    __syncthreads();
    for (int i = s + t; i < e; i += 512) {
        atomicAdd(&hc[col[i] >> 11], 1);
        atomicAdd(&hr[row[i] >> 11], 1);
    }
    __syncthreads();
    if (t < nsb) {
        int n = hc[t];
        hc[t] = n ? atomicAdd(&colAcur[t], n) : 0;
        n = hr[t];
        hr[t] = n ? atomicAdd(&rowAcur[t], n) : 0;
    }
    __syncthreads();
    for (int i = s + t; i < e; i += 512) {
        int r = row[i], c = col[i];
        float w = ew[i];
        int pc = atomicAdd(&hc[c >> 11], 1);
        if (pc < capA)
            colA[(size_t)(c >> 11) * capA + pc] =
                make_uint2(((unsigned)(c & 2047) << 17) | (unsigned)r, __float_as_uint(w));
        int pr = atomicAdd(&hr[r >> 11], 1);
        if (pr < capA)
            rowA[(size_t)(r >> 11) * capA + pr] = make_uint2((unsigned)r, __float_as_uint(w));
    }
}

// ---- level B: split each col super-bucket into 8 fine 256-node buckets ---
// fine bin f = meta>>25 (3 bits). colB record: meta2 = coff<<24 | r.
__global__ __launch_bounds__(512) void partB_kernel(
        const int* __restrict__ colAcur, const uint2* __restrict__ colA,
        int* __restrict__ colBcur, uint2* __restrict__ colB,
        int capA, int capB) {
    __shared__ int h[8];
    const int sb = blockIdx.x / NSPLIT;
    const int j = blockIdx.x % NSPLIT;
    const int t = threadIdx.x;
    const int cnt = min(colAcur[sb], capA);
    const int chunk = (cnt + NSPLIT - 1) / NSPLIT;
    const int s = j * chunk;
    const int e = min(cnt, s + chunk);
    if (t < 8) h[t] = 0;
    __syncthreads();
    const uint2* part = colA + (size_t)sb * capA;
    for (int i = s + t; i < e; i += 512) atomicAdd(&h[part[i].x >> 25], 1);
    __syncthreads();
    if (t < 8) {
        int n = h[t];
        h[t] = n ? atomicAdd(&colBcur[sb * 8 + t], n) : 0;
    }
    __syncthreads();
    for (int i = s + t; i < e; i += 512) {
        uint2 rec = part[i];
        int f = rec.x >> 25;
        int p = atomicAdd(&h[f], 1);
        if (p < capB) {
            unsigned coff = (rec.x >> 17) & 255u;
            unsigned r = rec.x & 0x1FFFFu;
            colB[(size_t)(sb * 8 + f) * capB + p] = make_uint2((coff << 24) | r, rec.y);
        }
    }
}

// ---- level B rows: per-super partial deg sums in LDS ---------------------
__global__ __launch_bounds__(512) void fine_rowp_kernel(
        const int* __restrict__ rowAcur, const uint2* __restrict__ rowA,
        float* __restrict__ partial, int capA) {
    __shared__ float sdeg[2048];
    const int sb = blockIdx.x / NSPLIT;
    const int j = blockIdx.x % NSPLIT;
    const int t = threadIdx.x;
    const int cnt = min(rowAcur[sb], capA);
    const int chunk = (cnt + NSPLIT - 1) / NSPLIT;
    const int s = j * chunk;
    const int e = min(cnt, s + chunk);
    for (int k = t; k < 2048; k += 512) sdeg[k] = 0.f;
    __syncthreads();
    const uint2* part = rowA + (size_t)sb * capA;
    for (int i = s + t; i < e; i += 512) {
        uint2 rec = part[i];
        atomicAdd(&sdeg[rec.x & 2047u], __uint_as_float(rec.y));
    }
    __syncthreads();
    float* dstp = partial + (size_t)blockIdx.x * 2048;
    for (int k = t; k < 2048; k += 512) dstp[k] = sdeg[k];
}

// ---- exclusive prefix over fine col-bucket sizes -------------------------
__global__ void colbase_scan_kernel(const int* __restrict__ colBcur,
                                    int* __restrict__ colbase,
                                    int* __restrict__ rowptr, int N, int nfb, int capB) {
    __shared__ int s[512];
    int t = threadIdx.x;
    int v = (t < nfb) ? min(colBcur[t], capB) : 0;
    s[t] = v;
    __syncthreads();
    for (int o = 1; o < 512; o <<= 1) {
        int u = (t >= o) ? s[t - o] : 0;
        __syncthreads();
        s[t] += u;
        __syncthreads();
    }
    if (t < nfb) colbase[t] = s[t] - v;
    if (t == 511) rowptr[N] = s[511];
}

// ---- per fine col-bucket CSR build (records grouped by col) --------------
__global__ __launch_bounds__(256) void fine_col_kernel(
        const int* __restrict__ colBcur, const int* __restrict__ colbase,
        const uint2* __restrict__ colB, const float* __restrict__ dis,
        uint2* __restrict__ erec, int* __restrict__ rowptr, int N, int capB) {
    __shared__ int h[256];
    __shared__ int sc[256];
    __shared__ int cur[256];
    const int b = blockIdx.x, t = threadIdx.x;
    const int sz = min(colBcur[b], capB);
    const uint2* part = colB + (size_t)b * capB;
    h[t] = 0;
    __syncthreads();
    for (int i = t; i < sz; i += 256) atomicAdd(&h[part[i].x >> 24], 1);
    __syncthreads();
    int v = h[t];
    sc[t] = v;
    __syncthreads();
    for (int o = 1; o < 256; o <<= 1) {
        int u = (t >= o) ? sc[t - o] : 0;
        __syncthreads();
        sc[t] += u;
        __syncthreads();
    }
    int excl = sc[t] - v;
    const int base = colbase[b];
    int c = (b << 8) + t;
    if (c < N) rowptr[c] = base + excl;
    cur[t] = excl;
    __syncthreads();
    for (int i = t; i < sz; i += 256) {
        uint2 rec = part[i];
        int coff = rec.x >> 24;
        int r = rec.x & 0xFFFFFFu;
        int pos = atomicAdd(&cur[coff], 1);
        float wd = __uint_as_float(rec.y) * dis[r];  // fold dis[row] into record
        erec[(size_t)base + pos] = make_uint2((unsigned)r, __float_as_uint(wd));
    }
}

// ---- fallback path (compact CSR, device-scope atomics) -------------------
__global__ void deg_count_kernel(const int* __restrict__ row, const int* __restrict__ col,
                                 const float* __restrict__ ew,
                                 float* __restrict__ deg, int* __restrict__ cnt, int E) {
    int e = blockIdx.x * 256 + threadIdx.x;
    if (e < E) {
        atomicAdd(&deg[row[e]], ew[e]);
        atomicAdd(&cnt[col[e]], 1);
    }
}

__global__ void scan1_kernel(const int* __restrict__ cnt, int* __restrict__ pre,
                             int* __restrict__ bsum, int N) {
    __shared__ int s[256];
    int t = threadIdx.x;
    int i = blockIdx.x * 256 + t;
    int v = (i < N) ? cnt[i] : 0;
    s[t] = v;
    __syncthreads();
    for (int o = 1; o < 256; o <<= 1) {
        int u = (t >= o) ? s[t - o] : 0;
        __syncthreads();
        s[t] += u;
        __syncthreads();
    }
    if (i < N) pre[i] = s[t] - v;
    if (t == 255) bsum[blockIdx.x] = s[255];
}

__global__ void scan2_kernel(const int* __restrict__ bsum, int* __restrict__ bpre, int nb) {
    __shared__ int s[512];
    int t = threadIdx.x;
    int v = (t < nb) ? bsum[t] : 0;
    s[t] = v;
    __syncthreads();
    for (int o = 1; o < 512; o <<= 1) {
        int u = (t >= o) ? s[t - o] : 0;
        __syncthreads();
        s[t] += u;
        __syncthreads();
    }
    if (t < nb) bpre[t] = s[t] - v;
}

__global__ void scan3_kernel(int* __restrict__ rowptr, int* __restrict__ cursor,
                             const int* __restrict__ bpre, int N, int E) {
    int i = blockIdx.x * 256 + threadIdx.x;
    if (i < N) {
        int v = rowptr[i] + bpre[i >> 8];
        rowptr[i] = v;
        cursor[i] = v;
    }
    if (i == 0) rowptr[N] = E;
}

__global__ void scatter_compact_kernel(const int* __restrict__ row, const int* __restrict__ col,
                                       const float* __restrict__ ew, int* __restrict__ cursor,
                                       uint2* __restrict__ erec, int E) {
    int e = blockIdx.x * 256 + threadIdx.x;
    if (e < E) {
        int p = atomicAdd(&cursor[col[e]], 1);
        erec[p] = make_uint2((unsigned)row[e], __float_as_uint(ew[e]));
    }
}

// ---- x -> bf16; dis from deg (mode 1) or 16-way partials (mode 2) --------
__global__ void cvt_dis_kernel(const float* __restrict__ x, unsigned short* __restrict__ xb,
                               const float* __restrict__ degp, float* __restrict__ dis,
                               int N, int total4, int mode) {
    int i = blockIdx.x * 256 + threadIdx.x;
    if (i < total4) {
        float4 v = reinterpret_cast<const float4*>(x)[i];
        ushort4 o;
        o.x = f2bf(v.x); o.y = f2bf(v.y); o.z = f2bf(v.z); o.w = f2bf(v.w);
        reinterpret_cast<ushort4*>(xb)[i] = o;
    }
    if (mode && i < N) {
        float d;
        if (mode == 2) {
            const float* p = degp + ((size_t)(i >> 11) * NSPLIT) * 2048 + (i & 2047);
            d = 0.f;
#pragma unroll
            for (int j = 0; j < NSPLIT; ++j) d += p[(size_t)j * 2048];
        } else {
            d = degp[i];
        }
        dis[i] = (d > 0.f) ? rsqrtf(d) : 0.f;
    }
}

// ---- gather prop: one wave per dst node, lane = channel ------------------
// premul=1: record.y already holds w*dis[row]; premul=0: multiply dis[row].
__global__ void gather_kernel(const int* __restrict__ ptr, const uint2* __restrict__ erec,
                              const float* __restrict__ dis,
                              const unsigned short* __restrict__ src,
                              unsigned short* __restrict__ dst, int N, int premul) {
    int node = blockIdx.x * 4 + (threadIdx.x >> 6);
    int lane = threadIdx.x & 63;
    if (node >= N) return;
    int s = ptr[node];
    int d = ptr[node + 1] - s;
    float acc = 0.f;
    for (int base = 0; base < d; base += 64) {
        int n = min(64, d - base);
        int ex = 0;
        float w = 0.f;
        if (lane < n) {
            uint2 e = erec[s + base + lane];
            ex = (int)e.x;
            w = __uint_as_float(e.y);
            if (!premul) w *= dis[ex];
        }
        int n4 = (n + 3) & ~3;
        for (int j = 0; j < n4; j += 4) {
            int r0 = __shfl(ex, j + 0, 64);
            int r1 = __shfl(ex, j + 1, 64);
            int r2 = __shfl(ex, j + 2, 64);
            int r3 = __shfl(ex, j + 3, 64);
            float w0 = __shfl(w, j + 0, 64);
            float w1 = __shfl(w, j + 1, 64);
            float w2 = __shfl(w, j + 2, 64);
            float w3 = __shfl(w, j + 3, 64);
            float v0 = bf2f(src[(size_t)r0 * 64 + lane]);
            float v1 = bf2f(src[(size_t)r1 * 64 + lane]);
            float v2 = bf2f(src[(size_t)r2 * 64 + lane]);
            float v3 = bf2f(src[(size_t)r3 * 64 + lane]);
            acc = fmaf(w0, v0, acc);
            acc = fmaf(w1, v1, acc);
            acc = fmaf(w2, v2, acc);
            acc = fmaf(w3, v3, acc);
        }
    }
    dst[(size_t)node * 64 + lane] = f2bf(-dis[node] * acc);
}

// ---- W pre-pack into swizzled bf16 LDS images ----------------------------
__global__ void prep_w_kernel(const float* __restrict__ W10, const float* __restrict__ W20,
                              const float* __restrict__ W21, const float* __restrict__ W30,
                              const float* __restrict__ W31, const float* __restrict__ W32,
                              unsigned short* __restrict__ imgW) {
    int i = blockIdx.x * 256 + threadIdx.x;
    if (i >= 6 * 7168) return;
    int img = i / 7168;
    int rem = i - img * 7168;
    int colc = rem >> 6;
    int k = rem & 63;
    const float* W;
    switch (img) {
        case 0: W = W10; break;
        case 1: W = W20; break;
        case 2: W = W21; break;
        case 3: W = W30; break;
        case 4: W = W31; break;
        default: W = W32; break;
    }
    float v = (colc < 100) ? W[k * 100 + colc] : 0.f;
    int g = k >> 3, j = k & 7;
    imgW[img * 7168 + colc * 64 + ((g ^ (colc & 7)) << 3) + j] = f2bf(v);
}

// ---- MFMA gemm: block = 64 rows x one segment (100 cols, padded 112) -----
__global__ __launch_bounds__(256) void gemm_mfma_kernel(
        const unsigned short* __restrict__ xb, const unsigned short* __restrict__ tx1b,
        const unsigned short* __restrict__ p2b, const unsigned short* __restrict__ imgW,
        const float* __restrict__ b1, const float* __restrict__ b2,
        const float* __restrict__ b3, float* __restrict__ out, int N) {
    __shared__ unsigned short Ft[64 * 64];
    __shared__ unsigned short Ws[112 * 64];
    const int bid = blockIdx.x;
    const int seg = bid % 3;
    const int tile = bid / 3;
    const int row0 = tile * 64;
    const int tid = threadIdx.x;
    const int wv = tid >> 6;
    const int l = tid & 63;
    const int m = l & 15;
    const int q = l >> 4;

    f32x4 acc[7];
#pragma unroll
    for (int t = 0; t < 7; ++t) acc[t] = (f32x4){0.f, 0.f, 0.f, 0.f};

    const int imgBase = (seg * (seg + 1) / 2) * 7168;

    for (int c = 0; c <= seg; ++c) {
        const unsigned short* __restrict__ src = (c == 0) ? xb : (c == 1) ? tx1b : p2b;
#pragma unroll
        for (int it = 0; it < 2; ++it) {
            int i = tid + it * 256;
            int r = i >> 3, g = i & 7;
            int grow = row0 + r;
            ushort8 v = {0, 0, 0, 0, 0, 0, 0, 0};
            if (grow < N) {
                v = *reinterpret_cast<const ushort8*>(src + (size_t)grow * 64 + g * 8);
                if (c == 2) {  // tx2 = 2*p2 - x on the fly
                    ushort8 xv = *reinterpret_cast<const ushort8*>(xb + (size_t)grow * 64 + g * 8);
#pragma unroll
                    for (int jj = 0; jj < 8; ++jj)
                        v[jj] = f2bf(2.f * bf2f(v[jj]) - bf2f(xv[jj]));
                }
            }
            *reinterpret_cast<ushort8*>(&Ft[r * 64 + ((g ^ (r & 7)) << 3)]) = v;
        }
        const uint4* wsrc = reinterpret_cast<const uint4*>(imgW + imgBase + c * 7168);
        uint4* wdst = reinterpret_cast<uint4*>(Ws);
#pragma unroll
        for (int it = 0; it < 4; ++it) {
            int i = tid + it * 256;
            if (i < 896) wdst[i] = wsrc[i];
        }
        __syncthreads();

        const int arow = wv * 16 + m;
#pragma unroll
        for (int ks = 0; ks < 2; ++ks) {
            short8 a = *reinterpret_cast<const short8*>(
                &Ft[arow * 64 + (((ks * 4 + q) ^ (arow & 7)) << 3)]);
#pragma unroll
            for (int t = 0; t < 7; ++t) {
                int n = t * 16 + m;
                short8 b = *reinterpret_cast<const short8*>(
                    &Ws[n * 64 + (((ks * 4 + q) ^ (n & 7)) << 3)]);
                acc[t] = __builtin_amdgcn_mfma_f32_16x16x32_bf16(a, b, acc[t], 0, 0, 0);
            }
        }
        __syncthreads();
    }

    const float* bsel = (seg == 0) ? b1 : (seg == 1) ? b2 : b3;
#pragma unroll
    for (int t = 0; t < 7; ++t) {
        int colseg = t * 16 + m;
        if (colseg >= 100) continue;
        float bv = bsel[colseg];
#pragma unroll
        for (int i = 0; i < 4; ++i) {
            int grow = row0 + wv * 16 + q * 4 + i;
            if (grow < N) out[(size_t)grow * 300 + seg * 100 + colseg] = acc[t][i] + bv;
        }
    }
}

extern "C" void kernel_launch(void* const* d_in, const int* in_sizes, int n_in,
                              void* d_out, int out_size, void* d_ws, size_t ws_size,
                              hipStream_t stream) {
    const float* x   = (const float*)d_in[0];
    const int*   ei  = (const int*)d_in[1];
    const float* ew  = (const float*)d_in[2];
    const float* W10 = (const float*)d_in[3];
    const float* b1  = (const float*)d_in[4];
    const float* W20 = (const float*)d_in[5];
    const float* W21 = (const float*)d_in[6];
    const float* b2  = (const float*)d_in[7];
    const float* W30 = (const float*)d_in[8];
    const float* W31 = (const float*)d_in[9];
    const float* W32 = (const float*)d_in[10];
    const float* b3  = (const float*)d_in[11];
    float* out = (float*)d_out;

    const int N = in_sizes[0] / 64;
    const int E = in_sizes[2];
    const int* row = ei;
    const int* col = ei + E;
    const int nb = (N + 255) / 256;
    const int eb = (E + 255) / 256;

    const int NSB = (N + 2047) >> 11;       // super-buckets (2048 nodes)
    const int nfb = NSB * 8;                // fine buckets (256 nodes)

    int total4 = N * 16;
    int pg = (N + 3) / 4;
    int ntile = (N + 63) / 64;

    // capacities with ~25% + constant slack
    long meanA = ((long)E * 2048 + N - 1) / N;
    int capA = (int)(meanA + meanA / 4 + 1024);
    long meanB = ((long)E * 256 + N - 1) / N;
    int capB = (int)(meanB + meanB / 4 + 512);

    char* base = (char*)d_ws;
    size_t off = 0;
    auto alloc = [&](size_t bytes) { size_t o = off; off = (off + bytes + 15) & ~(size_t)15; return o; };

    // ---- fixed allocations (shared by both paths) ----
    float* dis           = (float*)(base + alloc((size_t)4 * N));
    int*   rowptr        = (int*)(base + alloc((size_t)4 * (N + 1)));
    int*   colAcur       = (int*)(base + alloc((size_t)4 * 640));   // 64+64+512 cursors
    int*   rowAcur       = colAcur + 64;
    int*   colBcur       = colAcur + 128;
    int*   colbase       = (int*)(base + alloc((size_t)4 * 512));
    unsigned short* xb   = (unsigned short*)(base + alloc((size_t)128 * N));
    unsigned short* tx1b = (unsigned short*)(base + alloc((size_t)128 * N));
    unsigned short* p2b  = (unsigned short*)(base + alloc((size_t)128 * N));
    unsigned short* imgW = (unsigned short*)(base + alloc((size_t)2 * 6 * 7168));
    uint2* erec          = (uint2*)(base + alloc((size_t)8 * E));
    size_t mainfix = off;
    uint2* colA          = (uint2*)(base + alloc((size_t)8 * NSB * capA));
    uint2* rowA          = (uint2*)(base + alloc((size_t)8 * NSB * capA));
    uint2* colB          = (uint2*)(base + alloc((size_t)8 * nfb * capB));
    float* partial       = (float*)(base + alloc((size_t)4 * NSB * NSPLIT * 2048));
    size_t mainneed = off;

    bool mainok = (N <= 131072) && (NSB <= NSBMAX) && (nfb <= 512) && (mainneed <= ws_size);

    if (mainok) {
        const int PBLK = 512;
        int chunkA = (E + PBLK - 1) / PBLK;

        hipMemsetAsync(colAcur, 0, (size_t)4 * 640, stream);
        partA_kernel<<<PBLK, 512, 0, stream>>>(row, col, ew, colAcur, rowAcur,
                                               colA, rowA, E, NSB, chunkA, capA);
        partB_kernel<<<NSB * NSPLIT, 512, 0, stream>>>(colAcur, colA, colBcur, colB,
                                                       capA, capB);
        fine_rowp_kernel<<<NSB * NSPLIT, 512, 0, stream>>>(rowAcur, rowA, partial, capA);
        cvt_dis_kernel<<<(total4 + 255) / 256, 256, 0, stream>>>(x, xb, partial, dis,
                                                                 N, total4, 2);
        colbase_scan_kernel<<<1, 512, 0, stream>>>(colBcur, colbase, rowptr, N, nfb, capB);
        fine_col_kernel<<<nfb, 256, 0, stream>>>(colBcur, colbase, colB, dis,
                                                 erec, rowptr, N, capB);
        prep_w_kernel<<<(6 * 7168 + 255) / 256, 256, 0, stream>>>(W10, W20, W21, W30, W31, W32, imgW);

        gather_kernel<<<pg, 256, 0, stream>>>(rowptr, erec, dis, xb, tx1b, N, 1);
        gather_kernel<<<pg, 256, 0, stream>>>(rowptr, erec, dis, tx1b, p2b, N, 1);
        gemm_mfma_kernel<<<ntile * 3, 256, 0, stream>>>(xb, tx1b, p2b, imgW, b1, b2, b3, out, N);
    } else {
        // ---- compact-CSR fallback (device-scope atomics) ----
        off = mainfix;
        float* deg    = (float*)(base + alloc((size_t)4 * N));
        int*   cursor = (int*)(base + alloc((size_t)4 * N));
        int*   bsum   = (int*)(base + alloc((size_t)4 * nb));
        int*   bpre   = (int*)(base + alloc((size_t)4 * nb));

        hipMemsetAsync(deg, 0, (size_t)4 * N, stream);
        hipMemsetAsync(cursor, 0, (size_t)4 * N, stream);
        deg_count_kernel<<<eb, 256, 0, stream>>>(row, col, ew, deg, cursor, E);
        scan1_kernel<<<nb, 256, 0, stream>>>(cursor, rowptr, bsum, N);
        scan2_kernel<<<1, 512, 0, stream>>>(bsum, bpre, nb);
        scan3_kernel<<<nb, 256, 0, stream>>>(rowptr, cursor, bpre, N, E);
        scatter_compact_kernel<<<eb, 256, 0, stream>>>(row, col, ew, cursor, erec, E);
        cvt_dis_kernel<<<(total4 + 255) / 256, 256, 0, stream>>>(x, xb, deg, dis, N, total4, 1);
        prep_w_kernel<<<(6 * 7168 + 255) / 256, 256, 0, stream>>>(W10, W20, W21, W30, W31, W32, imgW);

        gather_kernel<<<pg, 256, 0, stream>>>(rowptr, erec, dis, xb, tx1b, N, 0);
        gather_kernel<<<pg, 256, 0, stream>>>(rowptr, erec, dis, tx1b, p2b, N, 0);
        gemm_mfma_kernel<<<ntile * 3, 256, 0, stream>>>(xb, tx1b, p2b, imgW, b1, b2, b3, out, N);
    }
}